// Round 9
// baseline (772.569 us; speedup 1.0000x reference)
//
#include <hip/hip_runtime.h>
#include <math.h>

// Problem constants
#define D_IN    512
#define HID     1024
#define CHUNK_L 256
#define NCHUNK  16
#define SEQ_L   4096
#define ROWS    1024      // 4 batches x 256 chunk rows
#define NROWS_T 16384     // total rows (4 x 4096)

typedef __attribute__((ext_vector_type(4))) float f32x4;
typedef __attribute__((ext_vector_type(8))) short bf16x8;
typedef __attribute__((ext_vector_type(4))) short bf16x4;

#define LOSS_SCALE (2.0f / 524288.0f)

__device__ __forceinline__ float gelu_f(float v) {
    return v * 0.5f * (1.0f + erff(v * 0.70710678118654752f));
}
__device__ __forceinline__ float dgelu_f(float v) {
    float cdf = 0.5f * (1.0f + erff(v * 0.70710678118654752f));
    float pdf = 0.3989422804014327f * expf(-0.5f * v * v);
    return cdf + v * pdf;
}
__device__ __forceinline__ float sigmoid_dev(float x) { return 1.0f / (1.0f + expf(-x)); }
__device__ __forceinline__ short f2b(float f) {
    unsigned u = __float_as_uint(f);
    u += 0x7fffu + ((u >> 16) & 1u);
    return (short)(u >> 16);
}
__device__ __forceinline__ float b2f(short s) {
    return __uint_as_float(((unsigned)(unsigned short)s) << 16);
}
// fp32 proven (R3); plausibility hedge kept for the 3 logits (|v| in [2.2,7])
__device__ __forceinline__ float read_scalar(const float* p) {
    float v = *p;
    if (fabsf(v) > 0.5f && fabsf(v) < 16.0f) return v;
    unsigned short lo = ((const unsigned short*)p)[0];
    return __uint_as_float(((unsigned)lo) << 16);
}

// global_load_lds width=16: wave-uniform LDS base + lane*16B dest; per-lane
// global source address (m104/m173).
__device__ __forceinline__ void glds16(const short* g, short* l) {
    __builtin_amdgcn_global_load_lds(
        (const __attribute__((address_space(1))) void*)g,
        (__attribute__((address_space(3))) void*)l, 16, 0, 0);
}

// ---------------------------------------------------------------------------
// GEMM core (R5-R8-proven): C_tile = A[m][k] @ B[n][k]^T, 64x64 tile, BK=64,
// 4 waves. global_load_lds staging into NSLOT rolling LDS window (16 KB/slot),
// counted vmcnt pipeline depth NSLOT-1, one s_barrier per k-block, XOR
// granule swizzle both sides (rule #21).
// R9: safe to call REPEATEDLY in an n-loop on the same KB window — next
// call's prologue slots 0..NSLOT-2 were last read >=1 barrier ago; the first
// in-loop issue (slot NSLOT-1) is behind the new call's j=0 barrier; the
// VMWAIT(0) at each call's last iteration drains vmcnt.
// ---------------------------------------------------------------------------
#define VMWAIT(N) asm volatile("s_waitcnt vmcnt(" #N ")" ::: "memory")

template<int NKB, int NSLOT>
__device__ __forceinline__ void tile_gemm2(
    const short* __restrict__ A, int lda,
    const short* __restrict__ B, int ldb,
    int m0, int n0, short* KB, f32x4 acc[2][2])
{
    const int tid = threadIdx.x;
    const int lane = tid & 63, wave = tid >> 6;
    const int wy = (wave >> 1) * 32, wx = (wave & 1) * 32;
    const int l16 = lane & 15, q = lane >> 4;

    // per-lane source granules (granule g: row=g>>3, col-slot j=g&7)
    const int ga = tid, gb = tid + 256;
    const int ra = ga >> 3, ja = ga & 7;
    const int rb = gb >> 3, jb = gb & 7;
    const short* sA0 = A + (size_t)(m0 + ra) * lda + ((ja ^ (ra & 7)) << 3);
    const short* sA1 = A + (size_t)(m0 + rb) * lda + ((jb ^ (rb & 7)) << 3);
    const short* sB0 = B + (size_t)(n0 + ra) * ldb + ((ja ^ (ra & 7)) << 3);
    const short* sB1 = B + (size_t)(n0 + rb) * ldb + ((jb ^ (rb & 7)) << 3);

    f32x4 z = {0.f, 0.f, 0.f, 0.f};
    acc[0][0] = z; acc[0][1] = z; acc[1][0] = z; acc[1][1] = z;

    auto issue = [&](int kb) {
        const int ko = kb << 6;                      // shorts along K
        short* d = KB + (kb % NSLOT) * 8192 + wave * 512;
        glds16(sA0 + ko, d);
        glds16(sA1 + ko, d + 2048);
        glds16(sB0 + ko, d + 4096);
        glds16(sB1 + ko, d + 6144);
    };
#pragma unroll
    for (int kb = 0; kb < NSLOT - 1 && kb < NKB; ++kb) issue(kb);

#pragma unroll
    for (int j = 0; j < NKB; ++j) {
        // allowed outstanding k-blocks ahead of j (compile-time after unroll)
        int ah = NKB - 1 - j; if (ah > NSLOT - 2) ah = NSLOT - 2;
        if      (ah >= 6) VMWAIT(24);
        else if (ah == 5) VMWAIT(20);
        else if (ah == 4) VMWAIT(16);
        else if (ah == 3) VMWAIT(12);
        else if (ah == 2) VMWAIT(8);
        else if (ah == 1) VMWAIT(4);
        else              VMWAIT(0);
        __builtin_amdgcn_s_barrier();
        __builtin_amdgcn_sched_barrier(0);
        if (j + NSLOT - 1 < NKB) issue(j + NSLOT - 1);
        const short* sl = KB + (j % NSLOT) * 8192;
#pragma unroll
        for (int ks = 0; ks < 2; ++ks) {
            bf16x8 af[2], bf[2];
#pragma unroll
            for (int i = 0; i < 2; ++i) {
                int row = wy + i * 16 + l16;
                af[i] = *(const bf16x8*)&sl[(row << 6) + (((ks * 4 + q) ^ (row & 7)) << 3)];
            }
#pragma unroll
            for (int jj = 0; jj < 2; ++jj) {
                int row = wx + jj * 16 + l16;
                bf[jj] = *(const bf16x8*)&sl[4096 + (row << 6) + (((ks * 4 + q) ^ (row & 7)) << 3)];
            }
#pragma unroll
            for (int i = 0; i < 2; ++i)
#pragma unroll
                for (int jj = 0; jj < 2; ++jj)
                    acc[i][jj] = __builtin_amdgcn_mfma_f32_16x16x32_bf16(af[i], bf[jj], acc[i][jj], 0, 0, 0);
        }
    }
}

// epilogue index helper (m89 C/D layout: col=lane&15, row=(lane>>4)*4+reg)
#define EPI_IDX() \
    const int tid_ = threadIdx.x; \
    const int wy_  = ((tid_ >> 6) >> 1) * 32; \
    const int wxl_ = ((tid_ >> 6) & 1) * 32; \
    const int q4_  = ((tid_ & 63) >> 4) * 4; \
    const int l16_ = tid_ & 15;

// ---------------------------------------------------------------------------
// init: fp32 masters + bf16 operand copies (single natural W2bn — R15)
// ---------------------------------------------------------------------------
__global__ __launch_bounds__(256)
void init_all(const float* __restrict__ w_q, const float* __restrict__ w_k,
              const float* __restrict__ w_v, const float* __restrict__ m1,
              const float* __restrict__ m2,
              float* __restrict__ W1f, float* __restrict__ W2f,
              float* __restrict__ S1, float* __restrict__ S2,
              short* __restrict__ WkvT, short* __restrict__ wqT,
              short* __restrict__ W1bT, short* __restrict__ W2bT,
              short* __restrict__ W2bn)
{
    int i = blockIdx.x * 256 + threadIdx.x;        // 0..524287
    float w1 = m1[i], w2 = m2[i];
    W1f[i] = w1; S1[i] = 0.f;
    W2f[i] = w2; S2[i] = 0.f;
    W2bn[i] = f2b(w2);                             // natural [1024 hid][512 d]
    int n9 = i >> 9, k9 = i & 511;
    W1bT[i] = f2b(m1[(size_t)k9 * HID + n9]);
    WkvT[i] = f2b(n9 < 512 ? w_k[(size_t)k9 * D_IN + n9]
                           : w_v[(size_t)k9 * D_IN + (n9 - 512)]);
    if (i < 262144) wqT[i] = f2b(w_q[(size_t)k9 * D_IN + n9]);
    int n10 = i >> 10, k10 = i & 1023;
    W2bT[i] = f2b(m2[(size_t)k10 * D_IN + n10]);
}

// ---------------------------------------------------------------------------
// x -> bf16 copy (bit-identical to the old in-core f2b rounding).
// ---------------------------------------------------------------------------
__global__ __launch_bounds__(256)
void xb_kernel(const float* __restrict__ x, short* __restrict__ xb)
{
    int i = blockIdx.x * 256 + threadIdx.x;        // 0..1048575
    f32x4 a = ((const f32x4*)x)[i * 2];
    f32x4 b = ((const f32x4*)x)[i * 2 + 1];
    bf16x8 o;
#pragma unroll
    for (int u = 0; u < 4; ++u) { o[u] = f2b(a[u]); o[u + 4] = f2b(b[u]); }
    ((bf16x8*)xb)[i] = o;
}

// ---------------------------------------------------------------------------
// R16 kvq: m-slab per block + inner n-loop (A reuse within block, L1/L2
// local). Grid 512, NSLOT=4 (64 KB) -> 2 blocks/CU, all resident.
// blocks 0..255: kv slab (t=bid>>4, ms=bid&15), 16 n-tiles.
// blocks 256..511: q slab (m0=(bid-256)*64), 8 n-tiles.
// ---------------------------------------------------------------------------
__global__ __launch_bounds__(256)
void kvq_kernel(const short* __restrict__ xb, const short* __restrict__ WkvT,
                const short* __restrict__ wqT,
                short* __restrict__ KVall, short* __restrict__ Ktall,
                short* __restrict__ qall)
{
    __shared__ short KB[4 * 8192];
    const int bid = blockIdx.x;
    EPI_IDX();
    f32x4 acc[2][2];
    if (bid < 256) {
        int t = bid >> 4, m0 = (bid & 15) * 64;
        // rows m0..m0+63 of the chunk view are contiguous in xb (64 | 256):
        const short* Akv = xb + ((size_t)(m0 >> 8) * SEQ_L + (size_t)t * CHUNK_L + (m0 & 255)) * D_IN;
        short* KV = KVall + (size_t)t * ROWS * 1024;
        short* Kt = Ktall + (size_t)t * D_IN * 1024;
        for (int nt = 0; nt < 16; ++nt) {
            int n0 = nt * 64;
            tile_gemm2<8, 4>(Akv, D_IN, WkvT, D_IN, 0, n0, KB, acc);
#pragma unroll
            for (int i = 0; i < 2; ++i)
#pragma unroll
                for (int j = 0; j < 2; ++j) {
                    int m = m0 + wy_ + i * 16 + q4_, n = n0 + wxl_ + j * 16 + l16_;
                    bf16x4 pk;
#pragma unroll
                    for (int r = 0; r < 4; ++r) {
                        short b = f2b(acc[i][j][r]);
                        KV[(size_t)(m + r) * 1024 + n] = b;
                        pk[r] = b;
                    }
                    if (n < 512) *(bf16x4*)&Kt[(size_t)n * 1024 + m] = pk;
                }
        }
    } else {
        int m0 = (bid - 256) * 64;                 // m over 16384 rows
        for (int nt = 0; nt < 8; ++nt) {
            int n0 = nt * 64;
            tile_gemm2<8, 4>(xb, D_IN, wqT, D_IN, m0, n0, KB, acc);
#pragma unroll
            for (int i = 0; i < 2; ++i)
#pragma unroll
                for (int j = 0; j < 2; ++j) {
                    int m = m0 + wy_ + i * 16 + q4_, n = n0 + wxl_ + j * 16 + l16_;
#pragma unroll
                    for (int r = 0; r < 4; ++r)
                        qall[(size_t)(m + r) * D_IN + n] = f2b(acc[i][j][r]);
                }
        }
    }
}

// ---------------------------------------------------------------------------
// h = k @ W1 -> Gb(gelu), GbT, DG(dgelu)   grid 256 (1/CU), NSLOT=8
// ---------------------------------------------------------------------------
__global__ __launch_bounds__(256)
void h_kernel(const short* __restrict__ KVt, const short* __restrict__ W1bT,
              short* __restrict__ Gb, short* __restrict__ GbT, short* __restrict__ DG)
{
    __shared__ short KB[8 * 8192];
    const int bid = blockIdx.x;
    EPI_IDX();
    int m0 = (bid & 15) * 64, n0 = (bid >> 4) * 64;
    f32x4 acc[2][2];
    tile_gemm2<8, 8>(KVt, 1024, W1bT, D_IN, m0, n0, KB, acc);
#pragma unroll
    for (int i = 0; i < 2; ++i)
#pragma unroll
        for (int j = 0; j < 2; ++j) {
            int m = m0 + wy_ + i * 16 + q4_, n = n0 + wxl_ + j * 16 + l16_;
            bf16x4 pg;
#pragma unroll
            for (int r = 0; r < 4; ++r) {
                float v = acc[i][j][r];
                float g = gelu_f(v);
                Gb[(size_t)(m + r) * 1024 + n] = f2b(g);
                DG[(size_t)(m + r) * 1024 + n] = f2b(dgelu_f(v));
                pg[r] = f2b(g);
            }
            *(bf16x4*)&GbT[(size_t)n * 1024 + m] = pg;
        }
}

// ---------------------------------------------------------------------------
// e = (Gb @ W2 - v)*LS -> KVt v-half in place + EVt   grid 128, NSLOT=8
// ---------------------------------------------------------------------------
__global__ __launch_bounds__(256)
void e_kernel(const short* __restrict__ Gb, const short* __restrict__ W2bT,
              short* __restrict__ KVt, short* __restrict__ EVt)
{
    __shared__ short KB[8 * 8192];
    const int bid = blockIdx.x;
    EPI_IDX();
    int m0 = (bid & 15) * 64, n0 = (bid >> 4) * 64;
    f32x4 acc[2][2];
    tile_gemm2<16, 8>(Gb, HID, W2bT, HID, m0, n0, KB, acc);
#pragma unroll
    for (int i = 0; i < 2; ++i)
#pragma unroll
        for (int j = 0; j < 2; ++j) {
            int m = m0 + wy_ + i * 16 + q4_, n = n0 + wxl_ + j * 16 + l16_;
            bf16x4 pe;
#pragma unroll
            for (int r = 0; r < 4; ++r) {
                size_t ci = (size_t)(m + r) * 1024 + 512 + n;
                float e = (acc[i][j][r] - b2f(KVt[ci])) * LOSS_SCALE;
                KVt[ci] = f2b(e);
                pe[r] = f2b(e);
            }
            *(bf16x4*)&EVt[(size_t)n * 1024 + m] = pe;
        }
}

// ---------------------------------------------------------------------------
// dh alone, grid 256 (1/CU), NSLOT=8. Reads natural W2bn (g2 overwrites it
// only in the NEXT launch).
// ---------------------------------------------------------------------------
__global__ __launch_bounds__(256)
void dh_kernel(const short* __restrict__ KVt, const short* __restrict__ W2bn,
               const short* __restrict__ DG, short* __restrict__ DHt)
{
    __shared__ short KB[8 * 8192];
    const int bid = blockIdx.x;
    EPI_IDX();
    int m0 = (bid & 15) * 64, n0 = (bid >> 4) * 64;
    f32x4 acc[2][2];
    tile_gemm2<8, 8>(KVt + 512, 1024, W2bn, D_IN, m0, n0, KB, acc);
#pragma unroll
    for (int i = 0; i < 2; ++i)
#pragma unroll
        for (int j = 0; j < 2; ++j) {
            int m = m0 + wy_ + i * 16 + q4_, n = n0 + wxl_ + j * 16 + l16_;
            bf16x4 pd;
#pragma unroll
            for (int r = 0; r < 4; ++r)
                pd[r] = f2b(acc[i][j][r] * b2f(DG[(size_t)(m + r) * 1024 + n]));
            *(bf16x4*)&DHt[(size_t)n * 1024 + m] = pd;
        }
}

// ---------------------------------------------------------------------------
// g2 + g1 in one 256-block launch (independent; R15-proven).
// blocks 0..127: g2 = Gb^T @ e, fused S2/W2 -> W2f,S2,W2bn,W2bT
// blocks 128..255: g1 = k^T @ dh, fused S1/W1 -> W1f,S1,W1bT
// ---------------------------------------------------------------------------
__global__ __launch_bounds__(256)
void g21_kernel(const short* __restrict__ GbT, const short* __restrict__ EVt,
                const short* __restrict__ Ktt, const short* __restrict__ DHt,
                float* __restrict__ W2f, float* __restrict__ S2,
                short* __restrict__ W2bT, short* __restrict__ W2bn,
                float* __restrict__ W1f, float* __restrict__ S1,
                short* __restrict__ W1bT,
                const float* __restrict__ ap, const float* __restrict__ lp,
                const float* __restrict__ dp, const int* __restrict__ um)
{
    __shared__ short KB[8 * 8192];
    const int bid = blockIdx.x;
    EPI_IDX();
    f32x4 acc[2][2];
    if (bid < 128) {
        int m0 = (bid & 15) * 64, n0 = (bid >> 4) * 64;   // m=hid (16), n=d (8)
        tile_gemm2<16, 8>(GbT, ROWS, EVt, ROWS, m0, n0, KB, acc);
        if (*um != 0) {
            const float alpha = sigmoid_dev(read_scalar(ap));
            const float lr    = sigmoid_dev(read_scalar(lp));
            const float decay = sigmoid_dev(read_scalar(dp));
#pragma unroll
            for (int i = 0; i < 2; ++i)
#pragma unroll
                for (int j = 0; j < 2; ++j) {
                    int m = m0 + wy_ + i * 16 + q4_, n = n0 + wxl_ + j * 16 + l16_;
                    bf16x4 pw;
#pragma unroll
                    for (int r = 0; r < 4; ++r) {
                        size_t ci = (size_t)(m + r) * D_IN + n;
                        float s = decay * S2[ci] - lr * acc[i][j][r];
                        S2[ci] = s;
                        float w = (1.0f - alpha) * W2f[ci] + s;
                        W2f[ci] = w;
                        W2bn[ci] = f2b(w);
                        pw[r] = f2b(w);
                    }
                    *(bf16x4*)&W2bT[(size_t)n * 1024 + m] = pw;
                }
        }
    } else {
        int idx = bid - 128;
        int m0 = (idx & 7) * 64, n0 = (idx >> 3) * 64;    // m=d (8), n=hid (16)
        tile_gemm2<16, 8>(Ktt, ROWS, DHt, ROWS, m0, n0, KB, acc);
        if (*um != 0) {
            const float alpha = sigmoid_dev(read_scalar(ap));
            const float lr    = sigmoid_dev(read_scalar(lp));
            const float decay = sigmoid_dev(read_scalar(dp));
#pragma unroll
            for (int i = 0; i < 2; ++i)
#pragma unroll
                for (int j = 0; j < 2; ++j) {
                    int m = m0 + wy_ + i * 16 + q4_, n = n0 + wxl_ + j * 16 + l16_;
                    bf16x4 pw;
#pragma unroll
                    for (int r = 0; r < 4; ++r) {
                        size_t ci = (size_t)(m + r) * HID + n;
                        float s = decay * S1[ci] - lr * acc[i][j][r];
                        S1[ci] = s;
                        float w = (1.0f - alpha) * W1f[ci] + s;
                        W1f[ci] = w;
                        pw[r] = f2b(w);
                    }
                    *(bf16x4*)&W1bT[(size_t)n * D_IN + m] = pw;
                }
        }
    }
}

// ---------------------------------------------------------------------------
// R16 fused readout: grid 256, 1 block per 64-row m-slab, NSLOT=8.
// Phase 1: Hro-slab = gelu(q @ W1), 16 n-tiles (A = own qall rows).
// vmcnt(0)+barrier (stores visible via write-through L2; L1 lines
// invalidated by own writes), then
// Phase 2: out-slab = Hro-slab @ W2, 8 n-tiles, K=1024 (A = OWN Hro rows —
// no grid sync needed). Replaces ro_h+ro_o (saves a launch + makes the Hro
// round-trip L2-local).
// ---------------------------------------------------------------------------
__global__ __launch_bounds__(256)
void ro_kernel(const short* __restrict__ qall, const short* __restrict__ W1bT,
               const short* __restrict__ W2bT, short* __restrict__ Hro,
               float* __restrict__ out)
{
    __shared__ short KB[8 * 8192];
    const int bid = blockIdx.x;
    EPI_IDX();
    const int m0 = bid * 64;
    f32x4 acc[2][2];

    for (int nt = 0; nt < 16; ++nt) {
        int n0 = nt * 64;
        tile_gemm2<8, 8>(qall, D_IN, W1bT, D_IN, m0, n0, KB, acc);
#pragma unroll
        for (int i = 0; i < 2; ++i)
#pragma unroll
            for (int j = 0; j < 2; ++j) {
                int m = m0 + wy_ + i * 16 + q4_, n = n0 + wxl_ + j * 16 + l16_;
#pragma unroll
                for (int r = 0; r < 4; ++r)
                    Hro[(size_t)(m + r) * HID + n] = f2b(gelu_f(acc[i][j][r]));
            }
    }

    VMWAIT(0);                         // own Hro stores retired
    __builtin_amdgcn_s_barrier();      // all waves' stores done before reads

    for (int nt = 0; nt < 8; ++nt) {
        int n0 = nt * 64;
        tile_gemm2<16, 8>(Hro, HID, W2bT, HID, m0, n0, KB, acc);
#pragma unroll
        for (int i = 0; i < 2; ++i)
#pragma unroll
            for (int j = 0; j < 2; ++j) {
                int m = m0 + wy_ + i * 16 + q4_, n = n0 + wxl_ + j * 16 + l16_;
#pragma unroll
                for (int r = 0; r < 4; ++r)
                    out[(size_t)(m + r) * D_IN + n] = acc[i][j][r];
            }
    }
}

// ---------------------------------------------------------------------------
// Host: 67 launches. Loop stages per chunk: h(256) e(128) dh(256) g21(256).
// ---------------------------------------------------------------------------
extern "C" void kernel_launch(void* const* d_in, const int* in_sizes, int n_in,
                              void* d_out, int out_size, void* d_ws, size_t ws_size,
                              hipStream_t stream)
{
    const float* x      = (const float*)d_in[0];
    const float* w_q    = (const float*)d_in[1];
    const float* w_k    = (const float*)d_in[2];
    const float* w_v    = (const float*)d_in[3];
    const float* mem_w1 = (const float*)d_in[4];
    const float* mem_w2 = (const float*)d_in[5];
    const float* ap     = (const float*)d_in[6];
    const float* lp     = (const float*)d_in[7];
    const float* dpp    = (const float*)d_in[8];
    const int*   um     = (const int*)d_in[9];
    float* out = (float*)d_out;

    const int nW = D_IN * HID;                 // 524288
    float* W1f = (float*)d_ws;
    float* W2f = W1f + nW;
    float* S1  = W2f + nW;
    float* S2  = S1 + nW;
    short* p   = (short*)(S2 + nW);
    short* WkvT = p;            p += nW;                    // [1024 n][512 k]
    short* wqT  = p;            p += 256 * 1024;            // [512][512]
    short* W1bT = p;            p += nW;                    // [1024 hid][512 d]
    short* W2bT = p;            p += nW;                    // [512 d][1024 hid]
    short* W2bn = p;            p += nW;                    // natural [1024 hid][512 d]
    short* Gb   = p;            p += ROWS * HID;
    short* GbT  = p;            p += ROWS * HID;
    short* DG   = p;            p += ROWS * HID;
    short* EVt  = p;            p += ROWS * D_IN;
    short* DHt  = p;            p += ROWS * HID;
    short* qall = p;            p += (size_t)NROWS_T * D_IN;        // 16 MB
    short* KVall = p;           p += (size_t)NCHUNK * ROWS * 1024;  // 32 MB
    short* Ktall = p;           p += (size_t)NCHUNK * D_IN * 1024;  // 16 MB
    short* Hro  = p;            p += (size_t)NROWS_T * HID;         // 32 MB
    short* xb   = p;            p += (size_t)NROWS_T * D_IN;        // 16 MB

    dim3 blk(256);
    hipLaunchKernelGGL(init_all, dim3(nW / 256), blk, 0, stream,
                       w_q, w_k, w_v, mem_w1, mem_w2,
                       W1f, W2f, S1, S2, WkvT, wqT, W1bT, W2bT, W2bn);
    hipLaunchKernelGGL(xb_kernel, dim3(4096), blk, 0, stream, x, xb);
    hipLaunchKernelGGL(kvq_kernel, dim3(512), blk, 0, stream,
                       xb, WkvT, wqT, KVall, Ktall, qall);

    for (int t = 0; t < NCHUNK; ++t) {
        short* KVt  = KVall + (size_t)t * ROWS * 1024;
        short* Ktt  = Ktall + (size_t)t * D_IN * 1024;
        hipLaunchKernelGGL(h_kernel, dim3(256), blk, 0, stream, KVt, W1bT, Gb, GbT, DG);
        hipLaunchKernelGGL(e_kernel, dim3(128), blk, 0, stream, Gb, W2bT, KVt, EVt);
        hipLaunchKernelGGL(dh_kernel, dim3(256), blk, 0, stream, KVt, W2bn, DG, DHt);
        hipLaunchKernelGGL(g21_kernel, dim3(256), blk, 0, stream,
                           GbT, EVt, Ktt, DHt, W2f, S2, W2bT, W2bn,
                           W1f, S1, W1bT, ap, lp, dpp, um);
    }

    hipLaunchKernelGGL(ro_kernel, dim3(256), blk, 0, stream,
                       qall, W1bT, W2bT, Hro, out);
}